// Round 5
// baseline (192.749 us; speedup 1.0000x reference)
//
#include <hip/hip_runtime.h>
#include <hip/hip_bf16.h>

#define BDIM 2
#define DDIM 128
#define HDIM 128
#define WDIM 128
#define CI 64
#define CO 64
#define NTAPS 27
#define GRID_CELLS (BDIM * DDIM * HDIM * WDIM)  // 4,194,304
#define NCBLK (GRID_CELLS / 256)                // 16384

typedef __attribute__((ext_vector_type(8))) short short8;
typedef __attribute__((ext_vector_type(4))) float floatx4;

// ws layout:
//   [0, 16 MB)        voxel grid (int)
//   +16 MB:   wt8     B-fragments, 256 KB
//   +16.25MB: bcnt    int[16384] block counts -> exclusive offsets (in place)
//   +~16.3MB: order   int[N] compacted, spatially sorted
//   +~17.3MB: zrow    256 B of zeros (invalid-gather target, any dtype)
//   +18 MB:   fb8     bf16 feats, N*CI*2 = 25.6 MB (only if ws_size allows)
#define WT_OFF   ((size_t)16 << 20)
#define BCNT_OFF (WT_OFF + ((size_t)256 << 10))
#define ORD_OFF  (BCNT_OFF + ((size_t)64 << 10))
#define ZROW_OFF (ORD_OFF + ((size_t)1 << 20))
#define FB_OFF   ((size_t)18 << 20)

typedef const __attribute__((address_space(1))) void* gas_t;
typedef __attribute__((address_space(3))) void* las_t;

__device__ __forceinline__ unsigned short f2bf(float f) {
    unsigned int u = __float_as_uint(f);
    return (unsigned short)((u + 0x7FFFu + ((u >> 16) & 1u)) >> 16);  // RNE
}

// Fused setup: blocks [0,54) weight->B-frag pack; block 54 zrow init;
// blocks [55, 55+nbf) feats f32->bf16; rest coord scatter.
// wt8[t*512 + (s*4+ot)*64 + l][j] = W[ot*16+(l&15)][t][s*32+(l>>4)*8+j]
__global__ __launch_bounds__(256) void setup_kernel(
    const int* __restrict__ coords, int* __restrict__ grid, int n,
    const float* __restrict__ weight, short8* __restrict__ wt8,
    float* __restrict__ zrow, const float* __restrict__ feats,
    short8* __restrict__ fb8, int nbf) {
    int bid = blockIdx.x, tid = threadIdx.x;
    if (bid < 54) {  // 54*256 == NTAPS*2*4*64 == 13824 exactly
        int idx = bid * 256 + tid;
        int l = idx & 63, ot = (idx >> 6) & 3, s = (idx >> 8) & 1, t = idx >> 9;
        int o = ot * 16 + (l & 15);
        int k0 = s * 32 + ((l >> 4) << 3);
        const float* src = weight + ((size_t)o * NTAPS + t) * CI + k0;
        short8 v;
#pragma unroll
        for (int j = 0; j < 8; ++j) v[j] = (short)f2bf(src[j]);
        wt8[idx] = v;
    } else if (bid == 54) {
        if (tid < 64) zrow[tid] = 0.f;
    } else if (bid < 55 + nbf) {  // feats -> bf16, 8 floats/thread
        int g = (bid - 55) * 256 + tid;
        if (g < n * 8) {
            const float* s = feats + (size_t)g * 8;
            short8 v;
#pragma unroll
            for (int j = 0; j < 8; ++j) v[j] = (short)f2bf(s[j]);
            fb8[g] = v;
        }
    } else {
        int i = (bid - 55 - nbf) * 256 + tid;
        if (i < n) {
            int4 c = ((const int4*)coords)[i];  // b, z, y, x
            grid[((c.x * DDIM + c.y) * HDIM + c.z) * WDIM + c.w] = i;
        }
    }
}

// ---- grid stream-compaction (spatial sort for free), no atomics ----
__global__ __launch_bounds__(256) void count_kernel(
    const int* __restrict__ grid, int* __restrict__ bcnt) {
    int i = blockIdx.x * 256 + threadIdx.x;
    unsigned long long b = __ballot(grid[i] >= 0);
    __shared__ int wc[4];
    if ((threadIdx.x & 63) == 0) wc[threadIdx.x >> 6] = __popcll(b);
    __syncthreads();
    if (threadIdx.x == 0) bcnt[blockIdx.x] = wc[0] + wc[1] + wc[2] + wc[3];
}

__global__ __launch_bounds__(1024) void scan_kernel(int* __restrict__ bcnt) {
    __shared__ int part[1024];
    int tid = threadIdx.x;
    int v[16], s = 0;
#pragma unroll
    for (int k = 0; k < 16; ++k) { v[k] = bcnt[tid * 16 + k]; s += v[k]; }
    part[tid] = s;
    __syncthreads();
    for (int off = 1; off < 1024; off <<= 1) {
        int t = (tid >= off) ? part[tid - off] : 0;
        __syncthreads();
        part[tid] += t;
        __syncthreads();
    }
    int ex = tid ? part[tid - 1] : 0;
#pragma unroll
    for (int k = 0; k < 16; ++k) { int nv = ex; ex += v[k]; bcnt[tid * 16 + k] = nv; }
}

__global__ __launch_bounds__(256) void emit_kernel(
    const int* __restrict__ grid, const int* __restrict__ boff,
    int* __restrict__ order) {
    int i = blockIdx.x * 256 + threadIdx.x;
    int v = grid[i];
    int lane = threadIdx.x & 63, w = threadIdx.x >> 6;
    unsigned long long b = __ballot(v >= 0);
    __shared__ int wc[4];
    if (lane == 0) wc[w] = __popcll(b);
    __syncthreads();
    int woff = 0;
    for (int k = 0; k < w; ++k) woff += wc[k];
    if (v >= 0) {
        int rank = __popcll(b & ((1ull << lane) - 1ull));
        order[boff[blockIdx.x] + woff + rank] = v;
    }
}

// ---- fused conv: block = 128 sorted points (4 waves x 32 rows) ----
// Each wave owns TWO 16-row A-tiles (a=0,1) -> 16 MFMAs per tap per wave,
// doubling compute per barrier vs the 16-row version; depth-2 prefetch now
// hides ~2x the gather latency.
// Sync skeleton (verified round 4): depth-2 pipeline, 4-deep LDS rotation,
// ONE barrier per tap, counted vmcnt (never 0 mid-loop).
//  - publish: counted VMW before the barrier covers own STAGE(t); barrier
//    makes all quarters visible.
//  - WAR: STAGE(t+2) at iter t overwrites bs[(t+2)&3], last read by
//    COMPUTE(t-2), which all waves finished before barrier(t-1).
// Probe table: lane (a<<5)|(q2<<4)|m holds taps {2i+q2} for tile a, row m.
template <bool BF>
__global__ __launch_bounds__(256) void conv_kernel(
    const float* __restrict__ feats, const short8* __restrict__ fb8,
    const short8* __restrict__ wt8, const float* __restrict__ bias,
    const int* __restrict__ coords, const int* __restrict__ grid,
    const int* __restrict__ order, const float* __restrict__ zrow,
    float* __restrict__ out, int n) {
    __shared__ short8 bs[4][512];  // 32 KB, 4-deep rotation
    int tid = threadIdx.x;
    int w = tid >> 6, l = tid & 63, quad = l >> 4, m = l & 15;
    int half = l >> 5, q2 = (l >> 4) & 1;

    // Oldest in vmcnt queue; drained by the first counted wait.
    float b0 = bias[m], b1 = bias[m + 16], b2 = bias[m + 32], b3 = bias[m + 48];

    // Lane's probe point: tile `half`, row m.
    int jrow = blockIdx.x * 128 + w * 32 + half * 16 + m;
    int j = jrow < n ? jrow : n - 1;
    int p = order[j];
    int4 c = ((const int4*)coords)[p];

    // Probe i covers tap t = 2*i + q2 for tile `half`, row m.
    int pr[14];
#pragma unroll
    for (int i = 0; i < 14; ++i) {
        int t = 2 * i + q2;
        int v = -1;
        if (t < NTAPS) {
            int dz = t / 9 - 1, rem = t % 9;
            int dy = rem / 3 - 1, dx = rem % 3 - 1;
            int nz = c.y + dz, ny = c.z + dy, nx = c.w + dx;
            if (nz >= 0 && nz < DDIM && ny >= 0 && ny < HDIM &&
                nx >= 0 && nx < WDIM)
                v = grid[((c.x * DDIM + nz) * HDIM + ny) * WDIM + nx];
        }
        pr[i] = v;
    }

    floatx4 acc[2][4];
#pragma unroll
    for (int a = 0; a < 2; ++a)
#pragma unroll
        for (int q = 0; q < 4; ++q) acc[a][q] = floatx4{0.f, 0.f, 0.f, 0.f};

    short8 xb[3][2][2];  // [slot][tile][khalf], static idx after unroll
    float4 xf[3][2][4];  // f32-path gather buffers
    int vval[3][2];

#define VMW(N) asm volatile("s_waitcnt vmcnt(" #N ")" ::: "memory")

    // Stage tap t's 8KB B-frag into bs[t&3]: 2 global_load_lds_dwordx4/lane.
#define STAGE(t)                                                              \
    {                                                                         \
        const short8* gsrc = wt8 + (size_t)(t) * 512 + w * 128 + l;           \
        __builtin_amdgcn_global_load_lds((gas_t)gsrc,                         \
            (las_t)&bs[(t) & 3][w * 128], 16, 0, 0);                          \
        __builtin_amdgcn_global_load_lds((gas_t)(gsrc + 64),                  \
            (las_t)&bs[(t) & 3][w * 128 + 64], 16, 0, 0);                     \
    }

    // Unconditional gathers for both tiles (zero row when invalid):
    // BF: 4 events/tap.  f32: 8 events/tap.
#define GATHER1(t, a)                                                         \
    {                                                                         \
        int vv = __shfl(pr[(t) >> 1], ((a) << 5) | (((t) & 1) << 4) | m);     \
        vval[(t) % 3][a] = vv;                                                \
        if constexpr (BF) {                                                   \
            const short8* ar =                                                \
                (vv >= 0 ? fb8 + (size_t)vv * 8 : (const short8*)zrow) + quad;\
            xb[(t) % 3][a][0] = ar[0];                                        \
            xb[(t) % 3][a][1] = ar[4];                                        \
        } else {                                                              \
            const float4* ar =                                                \
                (const float4*)(vv >= 0 ? feats + (size_t)vv * CI : zrow) +   \
                quad * 2;                                                     \
            float4* xp = xf[(t) % 3][a];                                      \
            xp[0] = ar[0]; xp[1] = ar[1]; xp[2] = ar[8]; xp[3] = ar[9];       \
        }                                                                     \
    }
#define GATHER(t) { GATHER1(t, 0); GATHER1(t, 1); }

#define COMPUTE1(t, a)                                                             \
    if (__ballot(vval[(t) % 3][a] >= 0) != 0ull) {                                 \
        short8 f0s, f1s;                                                           \
        if constexpr (BF) {                                                        \
            f0s = xb[(t) % 3][a][0];                                               \
            f1s = xb[(t) % 3][a][1];                                               \
        } else {                                                                   \
            const float4* g = xf[(t) % 3][a];                                      \
            union { short8 s; __hip_bfloat162 h[4]; } f0, f1;                      \
            f0.h[0] = __float22bfloat162_rn({g[0].x, g[0].y});                     \
            f0.h[1] = __float22bfloat162_rn({g[0].z, g[0].w});                     \
            f0.h[2] = __float22bfloat162_rn({g[1].x, g[1].y});                     \
            f0.h[3] = __float22bfloat162_rn({g[1].z, g[1].w});                     \
            f1.h[0] = __float22bfloat162_rn({g[2].x, g[2].y});                     \
            f1.h[1] = __float22bfloat162_rn({g[2].z, g[2].w});                     \
            f1.h[2] = __float22bfloat162_rn({g[3].x, g[3].y});                     \
            f1.h[3] = __float22bfloat162_rn({g[3].z, g[3].w});                     \
            f0s = f0.s; f1s = f1.s;                                                \
        }                                                                          \
        const short8* wb = &bs[(t) & 3][l];                                        \
        __builtin_amdgcn_s_setprio(1);                                             \
        acc[a][0] = __builtin_amdgcn_mfma_f32_16x16x32_bf16(f0s, wb[0 * 64], acc[a][0], 0, 0, 0); \
        acc[a][1] = __builtin_amdgcn_mfma_f32_16x16x32_bf16(f0s, wb[1 * 64], acc[a][1], 0, 0, 0); \
        acc[a][2] = __builtin_amdgcn_mfma_f32_16x16x32_bf16(f0s, wb[2 * 64], acc[a][2], 0, 0, 0); \
        acc[a][3] = __builtin_amdgcn_mfma_f32_16x16x32_bf16(f0s, wb[3 * 64], acc[a][3], 0, 0, 0); \
        acc[a][0] = __builtin_amdgcn_mfma_f32_16x16x32_bf16(f1s, wb[4 * 64], acc[a][0], 0, 0, 0); \
        acc[a][1] = __builtin_amdgcn_mfma_f32_16x16x32_bf16(f1s, wb[5 * 64], acc[a][1], 0, 0, 0); \
        acc[a][2] = __builtin_amdgcn_mfma_f32_16x16x32_bf16(f1s, wb[6 * 64], acc[a][2], 0, 0, 0); \
        acc[a][3] = __builtin_amdgcn_mfma_f32_16x16x32_bf16(f1s, wb[7 * 64], acc[a][3], 0, 0, 0); \
        __builtin_amdgcn_s_setprio(0);                                             \
    }
#define COMPUTE(t) { COMPUTE1(t, 0); COMPUTE1(t, 1); }

    // Prologue: prime taps 0 and 1.
    STAGE(0); GATHER(0);
    STAGE(1); GATHER(1);

    // Steady state at iter t's wait: in flight = taps t+1,t+2 (6 events each BF).
#pragma unroll
    for (int t = 0; t < NTAPS; ++t) {
        if (t + 2 < NTAPS) { STAGE(t + 2); GATHER(t + 2); }
        if constexpr (BF) {
            if (t < NTAPS - 2)       { VMW(12); }
            else if (t == NTAPS - 2) { VMW(6); }
            else                     { VMW(0); }
        } else {
            if (t < NTAPS - 2)       { VMW(20); }
            else if (t == NTAPS - 2) { VMW(10); }
            else                     { VMW(0); }
        }
        __builtin_amdgcn_sched_barrier(0);
        __builtin_amdgcn_s_barrier();       // all waves' STAGE(t) visible
        __builtin_amdgcn_sched_barrier(0);  // no LDS reads hoisted above
        COMPUTE(t);
        __builtin_amdgcn_sched_barrier(0);  // no LDS reads sunk below
    }

    // C layout: channel col = m, point row (within tile a) = quad*4 + reg.
#pragma unroll
    for (int a = 0; a < 2; ++a)
#pragma unroll
        for (int r = 0; r < 4; ++r) {
            int rr = quad * 4 + r;
            int jr = blockIdx.x * 128 + w * 32 + a * 16 + rr;
            int prow = __shfl(p, (a << 5) | rr);  // q2=0 lane of tile a, row rr
            if (jr < n) {
                float* orow = out + (size_t)prow * CO;
                orow[m]      = acc[a][0][r] + b0;
                orow[m + 16] = acc[a][1][r] + b1;
                orow[m + 32] = acc[a][2][r] + b2;
                orow[m + 48] = acc[a][3][r] + b3;
            }
        }
#undef STAGE
#undef GATHER
#undef GATHER1
#undef COMPUTE
#undef COMPUTE1
#undef VMW
}

extern "C" void kernel_launch(void* const* d_in, const int* in_sizes, int n_in,
                              void* d_out, int out_size, void* d_ws, size_t ws_size,
                              hipStream_t stream) {
    const float* feats  = (const float*)d_in[0];
    const float* weight = (const float*)d_in[1];
    const float* bias   = (const float*)d_in[2];
    const int*   coords = (const int*)d_in[3];
    float* out = (float*)d_out;
    int n = in_sizes[3] / 4;

    int*    grid  = (int*)d_ws;
    short8* wt8   = (short8*)((char*)d_ws + WT_OFF);
    int*    bcnt  = (int*)((char*)d_ws + BCNT_OFF);
    int*    order = (int*)((char*)d_ws + ORD_OFF);
    float*  zrow  = (float*)((char*)d_ws + ZROW_OFF);
    short8* fb8   = (short8*)((char*)d_ws + FB_OFF);

    int useBF = ws_size >= FB_OFF + (size_t)n * CI * 2;
    int nbf = useBF ? (n * 8 + 255) / 256 : 0;

    (void)hipMemsetAsync(grid, 0xFF, (size_t)GRID_CELLS * sizeof(int), stream);
    setup_kernel<<<55 + nbf + (n + 255) / 256, 256, 0, stream>>>(
        coords, grid, n, weight, wt8, zrow, feats, fb8, nbf);
    count_kernel<<<NCBLK, 256, 0, stream>>>(grid, bcnt);
    scan_kernel<<<1, 1024, 0, stream>>>(bcnt);
    emit_kernel<<<NCBLK, 256, 0, stream>>>(grid, bcnt, order);
    if (useBF)
        conv_kernel<true><<<(n + 127) / 128, 256, 0, stream>>>(
            feats, fb8, wt8, bias, coords, grid, order, zrow, out, n);
    else
        conv_kernel<false><<<(n + 127) / 128, 256, 0, stream>>>(
            feats, fb8, wt8, bias, coords, grid, order, zrow, out, n);
}

// Round 6
// 189.333 us; speedup vs baseline: 1.0180x; 1.0180x over previous
//
#include <hip/hip_runtime.h>
#include <hip/hip_bf16.h>

#define BDIM 2
#define DDIM 128
#define HDIM 128
#define WDIM 128
#define CI 64
#define CO 64
#define NTAPS 27
#define GRID_CELLS (BDIM * DDIM * HDIM * WDIM)  // 4,194,304
#define NCBLK (GRID_CELLS / 256)                // 16384

typedef __attribute__((ext_vector_type(8))) short short8;
typedef __attribute__((ext_vector_type(4))) float floatx4;

// ws layout:
//   [0, 16 MB)        voxel grid (int)
//   +16 MB:   wt8     B-fragments, 256 KB
//   +16.25MB: bcnt    int[16384] block counts -> exclusive offsets (in place)
//   +~16.3MB: order   int[N] compacted, spatially sorted
//   +~17.3MB: zrow    256 B of zeros (invalid-gather target, any dtype)
//   +18 MB:   fb8     bf16 feats, N*CI*2 = 25.6 MB (only if ws_size allows)
#define WT_OFF   ((size_t)16 << 20)
#define BCNT_OFF (WT_OFF + ((size_t)256 << 10))
#define ORD_OFF  (BCNT_OFF + ((size_t)64 << 10))
#define ZROW_OFF (ORD_OFF + ((size_t)1 << 20))
#define FB_OFF   ((size_t)18 << 20)

typedef const __attribute__((address_space(1))) void* gas_t;
typedef __attribute__((address_space(3))) void* las_t;

__device__ __forceinline__ unsigned short f2bf(float f) {
    unsigned int u = __float_as_uint(f);
    return (unsigned short)((u + 0x7FFFu + ((u >> 16) & 1u)) >> 16);  // RNE
}

// Fused setup: blocks [0,54) weight->B-frag pack; block 54 zrow init;
// blocks [55, 55+nbf) feats f32->bf16; rest coord scatter.
// wt8[t*512 + (s*4+ot)*64 + l][j] = W[ot*16+(l&15)][t][s*32+(l>>4)*8+j]
__global__ __launch_bounds__(256) void setup_kernel(
    const int* __restrict__ coords, int* __restrict__ grid, int n,
    const float* __restrict__ weight, short8* __restrict__ wt8,
    float* __restrict__ zrow, const float* __restrict__ feats,
    short8* __restrict__ fb8, int nbf) {
    int bid = blockIdx.x, tid = threadIdx.x;
    if (bid < 54) {  // 54*256 == NTAPS*2*4*64 == 13824 exactly
        int idx = bid * 256 + tid;
        int l = idx & 63, ot = (idx >> 6) & 3, s = (idx >> 8) & 1, t = idx >> 9;
        int o = ot * 16 + (l & 15);
        int k0 = s * 32 + ((l >> 4) << 3);
        const float* src = weight + ((size_t)o * NTAPS + t) * CI + k0;
        short8 v;
#pragma unroll
        for (int j = 0; j < 8; ++j) v[j] = (short)f2bf(src[j]);
        wt8[idx] = v;
    } else if (bid == 54) {
        if (tid < 64) zrow[tid] = 0.f;
    } else if (bid < 55 + nbf) {  // feats -> bf16, 8 floats/thread
        int g = (bid - 55) * 256 + tid;
        if (g < n * 8) {
            const float* s = feats + (size_t)g * 8;
            short8 v;
#pragma unroll
            for (int j = 0; j < 8; ++j) v[j] = (short)f2bf(s[j]);
            fb8[g] = v;
        }
    } else {
        int i = (bid - 55 - nbf) * 256 + tid;
        if (i < n) {
            int4 c = ((const int4*)coords)[i];  // b, z, y, x
            grid[((c.x * DDIM + c.y) * HDIM + c.z) * WDIM + c.w] = i;
        }
    }
}

// ---- grid stream-compaction (spatial sort for free), no atomics ----
__global__ __launch_bounds__(256) void count_kernel(
    const int* __restrict__ grid, int* __restrict__ bcnt) {
    int i = blockIdx.x * 256 + threadIdx.x;
    unsigned long long b = __ballot(grid[i] >= 0);
    __shared__ int wc[4];
    if ((threadIdx.x & 63) == 0) wc[threadIdx.x >> 6] = __popcll(b);
    __syncthreads();
    if (threadIdx.x == 0) bcnt[blockIdx.x] = wc[0] + wc[1] + wc[2] + wc[3];
}

__global__ __launch_bounds__(1024) void scan_kernel(int* __restrict__ bcnt) {
    __shared__ int part[1024];
    int tid = threadIdx.x;
    int v[16], s = 0;
#pragma unroll
    for (int k = 0; k < 16; ++k) { v[k] = bcnt[tid * 16 + k]; s += v[k]; }
    part[tid] = s;
    __syncthreads();
    for (int off = 1; off < 1024; off <<= 1) {
        int t = (tid >= off) ? part[tid - off] : 0;
        __syncthreads();
        part[tid] += t;
        __syncthreads();
    }
    int ex = tid ? part[tid - 1] : 0;
#pragma unroll
    for (int k = 0; k < 16; ++k) { int nv = ex; ex += v[k]; bcnt[tid * 16 + k] = nv; }
}

__global__ __launch_bounds__(256) void emit_kernel(
    const int* __restrict__ grid, const int* __restrict__ boff,
    int* __restrict__ order) {
    int i = blockIdx.x * 256 + threadIdx.x;
    int v = grid[i];
    int lane = threadIdx.x & 63, w = threadIdx.x >> 6;
    unsigned long long b = __ballot(v >= 0);
    __shared__ int wc[4];
    if (lane == 0) wc[w] = __popcll(b);
    __syncthreads();
    int woff = 0;
    for (int k = 0; k < w; ++k) woff += wc[k];
    if (v >= 0) {
        int rank = __popcll(b & ((1ull << lane) - 1ull));
        order[boff[blockIdx.x] + woff + rank] = v;
    }
}

// ---- fused conv: block = 128 sorted points (4 waves x 32 rows) ----
// XCD-aware bijective swizzle (m204): hardware assigns XCD = blockIdx % 8;
// remap so each XCD owns a CONTIGUOUS chunk of spatially-sorted blocks.
// Neighboring blocks share ~27x-reused gather rows -> per-XCD L2 (4 MB) now
// holds the chunk's fb8 rows (~3.2 MB) + grid slab (~2 MB): gathers become
// L2 hits instead of cross-XCD L3 round-trips.
// Sync skeleton (verified rounds 4-5): depth-2 pipeline, 4-deep LDS
// rotation, ONE barrier per tap, counted vmcnt (never 0 mid-loop).
template <bool BF>
__global__ __launch_bounds__(256) void conv_kernel(
    const float* __restrict__ feats, const short8* __restrict__ fb8,
    const short8* __restrict__ wt8, const float* __restrict__ bias,
    const int* __restrict__ coords, const int* __restrict__ grid,
    const int* __restrict__ order, const float* __restrict__ zrow,
    float* __restrict__ out, int n) {
    __shared__ short8 bs[4][512];  // 32 KB, 4-deep rotation
    int tid = threadIdx.x;
    int w = tid >> 6, l = tid & 63, quad = l >> 4, m = l & 15;
    int half = l >> 5, q2 = (l >> 4) & 1;

    // Bijective XCD swizzle: XCD k gets logical blocks [base_k, base_k+cnt_k).
    int nwg = gridDim.x, orig = blockIdx.x;
    int q = nwg >> 3, r = nwg & 7, xcd = orig & 7;
    int bswz = (xcd < r ? xcd * (q + 1) : r * (q + 1) + (xcd - r) * q) +
               (orig >> 3);

    // Oldest in vmcnt queue; drained by the first counted wait.
    float b0 = bias[m], b1 = bias[m + 16], b2 = bias[m + 32], b3 = bias[m + 48];

    // Lane's probe point: tile `half`, row m.
    int jrow = bswz * 128 + w * 32 + half * 16 + m;
    int j = jrow < n ? jrow : n - 1;
    int p = order[j];
    int4 c = ((const int4*)coords)[p];

    // Probe i covers tap t = 2*i + q2 for tile `half`, row m.
    int pr[14];
#pragma unroll
    for (int i = 0; i < 14; ++i) {
        int t = 2 * i + q2;
        int v = -1;
        if (t < NTAPS) {
            int dz = t / 9 - 1, rem = t % 9;
            int dy = rem / 3 - 1, dx = rem % 3 - 1;
            int nz = c.y + dz, ny = c.z + dy, nx = c.w + dx;
            if (nz >= 0 && nz < DDIM && ny >= 0 && ny < HDIM &&
                nx >= 0 && nx < WDIM)
                v = grid[((c.x * DDIM + nz) * HDIM + ny) * WDIM + nx];
        }
        pr[i] = v;
    }

    floatx4 acc[2][4];
#pragma unroll
    for (int a = 0; a < 2; ++a)
#pragma unroll
        for (int qq = 0; qq < 4; ++qq) acc[a][qq] = floatx4{0.f, 0.f, 0.f, 0.f};

    short8 xb[3][2][2];  // [slot][tile][khalf], static idx after unroll
    float4 xf[3][2][4];  // f32-path gather buffers
    int vval[3][2];

#define VMW(N) asm volatile("s_waitcnt vmcnt(" #N ")" ::: "memory")

    // Stage tap t's 8KB B-frag into bs[t&3]: 2 global_load_lds_dwordx4/lane.
#define STAGE(t)                                                              \
    {                                                                         \
        const short8* gsrc = wt8 + (size_t)(t) * 512 + w * 128 + l;           \
        __builtin_amdgcn_global_load_lds((gas_t)gsrc,                         \
            (las_t)&bs[(t) & 3][w * 128], 16, 0, 0);                          \
        __builtin_amdgcn_global_load_lds((gas_t)(gsrc + 64),                  \
            (las_t)&bs[(t) & 3][w * 128 + 64], 16, 0, 0);                     \
    }

    // Unconditional gathers for both tiles (zero row when invalid):
    // BF: 4 events/tap.  f32: 8 events/tap.
#define GATHER1(t, a)                                                         \
    {                                                                         \
        int vv = __shfl(pr[(t) >> 1], ((a) << 5) | (((t) & 1) << 4) | m);     \
        vval[(t) % 3][a] = vv;                                                \
        if constexpr (BF) {                                                   \
            const short8* ar =                                                \
                (vv >= 0 ? fb8 + (size_t)vv * 8 : (const short8*)zrow) + quad;\
            xb[(t) % 3][a][0] = ar[0];                                        \
            xb[(t) % 3][a][1] = ar[4];                                        \
        } else {                                                              \
            const float4* ar =                                                \
                (const float4*)(vv >= 0 ? feats + (size_t)vv * CI : zrow) +   \
                quad * 2;                                                     \
            float4* xp = xf[(t) % 3][a];                                      \
            xp[0] = ar[0]; xp[1] = ar[1]; xp[2] = ar[8]; xp[3] = ar[9];       \
        }                                                                     \
    }
#define GATHER(t) { GATHER1(t, 0); GATHER1(t, 1); }

#define COMPUTE1(t, a)                                                             \
    if (__ballot(vval[(t) % 3][a] >= 0) != 0ull) {                                 \
        short8 f0s, f1s;                                                           \
        if constexpr (BF) {                                                        \
            f0s = xb[(t) % 3][a][0];                                               \
            f1s = xb[(t) % 3][a][1];                                               \
        } else {                                                                   \
            const float4* g = xf[(t) % 3][a];                                      \
            union { short8 s; __hip_bfloat162 h[4]; } f0, f1;                      \
            f0.h[0] = __float22bfloat162_rn({g[0].x, g[0].y});                     \
            f0.h[1] = __float22bfloat162_rn({g[0].z, g[0].w});                     \
            f0.h[2] = __float22bfloat162_rn({g[1].x, g[1].y});                     \
            f0.h[3] = __float22bfloat162_rn({g[1].z, g[1].w});                     \
            f1.h[0] = __float22bfloat162_rn({g[2].x, g[2].y});                     \
            f1.h[1] = __float22bfloat162_rn({g[2].z, g[2].w});                     \
            f1.h[2] = __float22bfloat162_rn({g[3].x, g[3].y});                     \
            f1.h[3] = __float22bfloat162_rn({g[3].z, g[3].w});                     \
            f0s = f0.s; f1s = f1.s;                                                \
        }                                                                          \
        const short8* wb = &bs[(t) & 3][l];                                        \
        __builtin_amdgcn_s_setprio(1);                                             \
        acc[a][0] = __builtin_amdgcn_mfma_f32_16x16x32_bf16(f0s, wb[0 * 64], acc[a][0], 0, 0, 0); \
        acc[a][1] = __builtin_amdgcn_mfma_f32_16x16x32_bf16(f0s, wb[1 * 64], acc[a][1], 0, 0, 0); \
        acc[a][2] = __builtin_amdgcn_mfma_f32_16x16x32_bf16(f0s, wb[2 * 64], acc[a][2], 0, 0, 0); \
        acc[a][3] = __builtin_amdgcn_mfma_f32_16x16x32_bf16(f0s, wb[3 * 64], acc[a][3], 0, 0, 0); \
        acc[a][0] = __builtin_amdgcn_mfma_f32_16x16x32_bf16(f1s, wb[4 * 64], acc[a][0], 0, 0, 0); \
        acc[a][1] = __builtin_amdgcn_mfma_f32_16x16x32_bf16(f1s, wb[5 * 64], acc[a][1], 0, 0, 0); \
        acc[a][2] = __builtin_amdgcn_mfma_f32_16x16x32_bf16(f1s, wb[6 * 64], acc[a][2], 0, 0, 0); \
        acc[a][3] = __builtin_amdgcn_mfma_f32_16x16x32_bf16(f1s, wb[7 * 64], acc[a][3], 0, 0, 0); \
        __builtin_amdgcn_s_setprio(0);                                             \
    }
#define COMPUTE(t) { COMPUTE1(t, 0); COMPUTE1(t, 1); }

    // Prologue: prime taps 0 and 1.
    STAGE(0); GATHER(0);
    STAGE(1); GATHER(1);

    // Steady state at iter t's wait: in flight = taps t+1,t+2 (6 events each BF).
#pragma unroll
    for (int t = 0; t < NTAPS; ++t) {
        if (t + 2 < NTAPS) { STAGE(t + 2); GATHER(t + 2); }
        if constexpr (BF) {
            if (t < NTAPS - 2)       { VMW(12); }
            else if (t == NTAPS - 2) { VMW(6); }
            else                     { VMW(0); }
        } else {
            if (t < NTAPS - 2)       { VMW(20); }
            else if (t == NTAPS - 2) { VMW(10); }
            else                     { VMW(0); }
        }
        __builtin_amdgcn_sched_barrier(0);
        __builtin_amdgcn_s_barrier();       // all waves' STAGE(t) visible
        __builtin_amdgcn_sched_barrier(0);  // no LDS reads hoisted above
        COMPUTE(t);
        __builtin_amdgcn_sched_barrier(0);  // no LDS reads sunk below
    }

    // C layout: channel col = m, point row (within tile a) = quad*4 + reg.
#pragma unroll
    for (int a = 0; a < 2; ++a)
#pragma unroll
        for (int rr4 = 0; rr4 < 4; ++rr4) {
            int rr = quad * 4 + rr4;
            int jr = bswz * 128 + w * 32 + a * 16 + rr;
            int prow = __shfl(p, (a << 5) | rr);  // q2=0 lane of tile a, row rr
            if (jr < n) {
                float* orow = out + (size_t)prow * CO;
                orow[m]      = acc[a][0][rr4] + b0;
                orow[m + 16] = acc[a][1][rr4] + b1;
                orow[m + 32] = acc[a][2][rr4] + b2;
                orow[m + 48] = acc[a][3][rr4] + b3;
            }
        }
#undef STAGE
#undef GATHER
#undef GATHER1
#undef COMPUTE
#undef COMPUTE1
#undef VMW
}

extern "C" void kernel_launch(void* const* d_in, const int* in_sizes, int n_in,
                              void* d_out, int out_size, void* d_ws, size_t ws_size,
                              hipStream_t stream) {
    const float* feats  = (const float*)d_in[0];
    const float* weight = (const float*)d_in[1];
    const float* bias   = (const float*)d_in[2];
    const int*   coords = (const int*)d_in[3];
    float* out = (float*)d_out;
    int n = in_sizes[3] / 4;

    int*    grid  = (int*)d_ws;
    short8* wt8   = (short8*)((char*)d_ws + WT_OFF);
    int*    bcnt  = (int*)((char*)d_ws + BCNT_OFF);
    int*    order = (int*)((char*)d_ws + ORD_OFF);
    float*  zrow  = (float*)((char*)d_ws + ZROW_OFF);
    short8* fb8   = (short8*)((char*)d_ws + FB_OFF);

    int useBF = ws_size >= FB_OFF + (size_t)n * CI * 2;
    int nbf = useBF ? (n * 8 + 255) / 256 : 0;

    (void)hipMemsetAsync(grid, 0xFF, (size_t)GRID_CELLS * sizeof(int), stream);
    setup_kernel<<<55 + nbf + (n + 255) / 256, 256, 0, stream>>>(
        coords, grid, n, weight, wt8, zrow, feats, fb8, nbf);
    count_kernel<<<NCBLK, 256, 0, stream>>>(grid, bcnt);
    scan_kernel<<<1, 1024, 0, stream>>>(bcnt);
    emit_kernel<<<NCBLK, 256, 0, stream>>>(grid, bcnt, order);
    if (useBF)
        conv_kernel<true><<<(n + 127) / 128, 256, 0, stream>>>(
            feats, fb8, wt8, bias, coords, grid, order, zrow, out, n);
    else
        conv_kernel<false><<<(n + 127) / 128, 256, 0, stream>>>(
            feats, fb8, wt8, bias, coords, grid, order, zrow, out, n);
}